// Round 8
// baseline (126.225 us; speedup 1.0000x reference)
//
#include <hip/hip_runtime.h>
#include <hip/hip_bf16.h>
#include <cstdint>
#include <cstddef>

#define BB 2
#define SS 2048
#define DD 1024
#define HH 16
#define EE 64

typedef short bf16x8 __attribute__((ext_vector_type(8)));
typedef short s4 __attribute__((ext_vector_type(4)));
typedef float f32x4 __attribute__((ext_vector_type(4)));
typedef float float4v __attribute__((ext_vector_type(4)));
typedef unsigned int u32x2 __attribute__((ext_vector_type(2)));

#define GLDS(gp, lp) __builtin_amdgcn_global_load_lds( \
    (const __attribute__((address_space(1))) void*)(gp), \
    (__attribute__((address_space(3))) void*)(lp), 16, 0, 0)

static __device__ __forceinline__ short f2bf(float f) {
    union { float f; uint32_t u; } v; v.f = f;
    uint32_t r = (v.u + 0x7fffu + ((v.u >> 16) & 1u)) >> 16;
    return (short)r;
}

// packed f32x2 -> bf16x2 (RNE), single HW op
static __device__ __forceinline__ uint32_t cvtpk(float a, float b) {
    uint32_t r;
    asm("v_cvt_pk_bf16_f32 %0, %1, %2" : "=v"(r) : "v"(a), "v"(b));
    return r;
}

// ---------------- fp32 -> bf16 convert (vectorized) ----------------
__global__ void convert_x_kernel(const float* __restrict__ x, short* __restrict__ xb, int n4) {
    int i = blockIdx.x * blockDim.x + threadIdx.x;
    if (i >= n4) return;
    float4v v = ((const float4v*)x)[i];
    s4 o; o[0] = f2bf(v[0]); o[1] = f2bf(v[1]); o[2] = f2bf(v[2]); o[3] = f2bf(v[3]);
    ((s4*)xb)[i] = o;
}

// ------------- weight transpose+convert: 3x [16][1024 x 64] -> [16][64 x 1024] bf16 -------------
__global__ void transpose_w3_kernel(const float* __restrict__ Wq,
                                    const float* __restrict__ Wk,
                                    const float* __restrict__ Wv,
                                    short* __restrict__ dst) {
    __shared__ float tile[64][65];
    int which = blockIdx.y >> 4;
    int mtx = blockIdx.y & 15;
    const float* src = (which == 0) ? Wq : (which == 1) ? Wk : Wv;
    int r0 = blockIdx.x * 64;
    const float* s = src + (size_t)mtx * DD * 64;
    short* d = dst + (size_t)which * HH * EE * DD + (size_t)mtx * DD * 64;
    int t = threadIdx.x;
#pragma unroll
    for (int i = 0; i < 16; ++i) {
        int idx = t + i * 256;
        int r = idx >> 6, c = idx & 63;
        tile[r][c] = s[(size_t)(r0 + r) * 64 + c];
    }
    __syncthreads();
#pragma unroll
    for (int i = 0; i < 16; ++i) {
        int idx = t + i * 256;
        int e = idx >> 6, dd2 = idx & 63;
        d[(size_t)e * DD + r0 + dd2] = f2bf(tile[dd2][e]);
    }
}

__global__ void transpose_w_kernel(const float* __restrict__ src, short* __restrict__ dst, int R) {
    __shared__ float tile[64][65];
    int r0 = blockIdx.x * 64;
    int t = threadIdx.x;
#pragma unroll
    for (int i = 0; i < 16; ++i) {
        int idx = t + i * 256;
        int r = idx >> 6, c = idx & 63;
        tile[r][c] = src[(size_t)(r0 + r) * 64 + c];
    }
    __syncthreads();
#pragma unroll
    for (int i = 0; i < 16; ++i) {
        int idx = t + i * 256;
        int e = idx >> 6, dd2 = idx & 63;
        dst[(size_t)e * R + r0 + dd2] = f2bf(tile[dd2][e]);
    }
}

// ------------- QKV GEMM: 256x256 tile, BK=32, 8 waves, triple-buffer, counted vmcnt -------------
__global__ __launch_bounds__(512, 2) void qkv_gemm(const short* __restrict__ A,
                                                   const short* __restrict__ Bt,
                                                   short* __restrict__ Qo,
                                                   short* __restrict__ Ko,
                                                   short* __restrict__ Vto) {
    __shared__ __align__(16) short As3[3][128 * 64];
    __shared__ __align__(16) short Bs3[3][128 * 64];
    int tid = threadIdx.x;
    int wv = tid >> 6, lane = tid & 63;
    int m = lane & 15, g = lane >> 4;
    int wr = wv >> 2, wc = wv & 3;

    int xcd = blockIdx.x & 7, idx = blockIdx.x >> 3;
    int mb = (xcd & 3) * 4 + (idx & 3);
    int nb = (xcd >> 2) * 6 + (idx >> 2);
    int rowBase = mb * 256, colBase0 = nb * 256;

    int src_row[2], src_kcol[2];
#pragma unroll
    for (int j = 0; j < 2; ++j) {
        int si = j * 512 + tid;
        int sr = si >> 3, sp = si & 7;
        int sl = sp ^ (sr & 7);
        src_row[j] = 2 * sr + (sl >> 2);
        src_kcol[j] = (sl & 3) * 8;
    }
    const short* aP0 = A + (size_t)(rowBase + src_row[0]) * DD + src_kcol[0];
    const short* aP1 = A + (size_t)(rowBase + src_row[1]) * DD + src_kcol[1];
    const short* bP0 = Bt + (size_t)(colBase0 + src_row[0]) * DD + src_kcol[0];
    const short* bP1 = Bt + (size_t)(colBase0 + src_row[1]) * DD + src_kcol[1];
    int dst0 = (wv * 64) * 8;
    int dst1 = (512 + wv * 64) * 8;

    f32x4 acc[8][4];
#pragma unroll
    for (int i = 0; i < 8; ++i)
#pragma unroll
        for (int j = 0; j < 4; ++j) acc[i][j] = {0, 0, 0, 0};

    int rdoff = ((m & 1) * 64 + g * 16) ^ (((m >> 1) & 7) << 4);
    int mh = m >> 1;

    auto STAGE = [&](int buf, int kt) {
        short* ab = &As3[buf][0];
        short* bb = &Bs3[buf][0];
        GLDS(aP0 + kt, ab + dst0);
        GLDS(aP1 + kt, ab + dst1);
        GLDS(bP0 + kt, bb + dst0);
        GLDS(bP1 + kt, bb + dst1);
    };

    auto COMPUTE = [&](int buf) {
        bf16x8 af[8], bfr[4];
#pragma unroll
        for (int mi = 0; mi < 8; ++mi)
            af[mi] = *(const bf16x8*)((const char*)&As3[buf][(wr * 64 + mi * 8 + mh) * 64] + rdoff);
#pragma unroll
        for (int ni = 0; ni < 4; ++ni)
            bfr[ni] = *(const bf16x8*)((const char*)&Bs3[buf][(wc * 32 + ni * 8 + mh) * 64] + rdoff);
        asm volatile("s_waitcnt lgkmcnt(0)\ns_barrier" ::: "memory");
        __builtin_amdgcn_s_setprio(1);
#pragma unroll
        for (int mi = 0; mi < 8; ++mi)
#pragma unroll
            for (int ni = 0; ni < 4; ++ni)
                acc[mi][ni] = __builtin_amdgcn_mfma_f32_16x16x32_bf16(af[mi], bfr[ni], acc[mi][ni], 0, 0, 0);
        __builtin_amdgcn_s_setprio(0);
    };

    STAGE(0, 0);
    STAGE(1, 32);
    for (int t = 0; t < 30; ++t) {
        STAGE((t + 2) % 3, (t + 2) * 32);
        asm volatile("s_waitcnt vmcnt(8)\ns_barrier" ::: "memory");
        COMPUTE(t % 3);
    }
    asm volatile("s_waitcnt vmcnt(4)\ns_barrier" ::: "memory");
    COMPUTE(0);
    asm volatile("s_waitcnt vmcnt(0)\ns_barrier" ::: "memory");
    COMPUTE(1);

    int colw = colBase0 + wc * 64;
    int mtx = colw >> 10;
    int h = (colw >> 6) & 15;
    int rb = rowBase + wr * 128;

    if (mtx == 0) {
        // Q pre-scaled by 1/8 * log2(e) so attention can use exp2 directly
        const float qs = 0.125f * 1.44269504089f;
#pragma unroll
        for (int mi = 0; mi < 8; ++mi)
#pragma unroll
            for (int ni = 0; ni < 4; ++ni)
#pragma unroll
                for (int r = 0; r < 4; ++r) {
                    int row = rb + mi * 16 + g * 4 + r;
                    int b = row >> 11, s = row & 2047;
                    Qo[((size_t)(b * HH + h) * SS + s) * EE + ni * 16 + m] = f2bf(acc[mi][ni][r] * qs);
                }
    } else if (mtx == 1) {
#pragma unroll
        for (int mi = 0; mi < 8; ++mi)
#pragma unroll
            for (int ni = 0; ni < 4; ++ni)
#pragma unroll
                for (int r = 0; r < 4; ++r) {
                    int row = rb + mi * 16 + g * 4 + r;
                    int b = row >> 11, s = row & 2047;
                    Ko[((size_t)(b * HH + h) * SS + s) * EE + ni * 16 + m] = f2bf(acc[mi][ni][r]);
                }
    } else {
#pragma unroll
        for (int mi = 0; mi < 8; ++mi)
#pragma unroll
            for (int ni = 0; ni < 4; ++ni) {
                int row0 = rb + mi * 16 + g * 4;
                int b = row0 >> 11, s = row0 & 2047;
                s4 o; o[0] = f2bf(acc[mi][ni][0]); o[1] = f2bf(acc[mi][ni][1]);
                o[2] = f2bf(acc[mi][ni][2]); o[3] = f2bf(acc[mi][ni][3]);
                *(s4*)&Vto[((size_t)(b * HH + h) * EE + ni * 16 + m) * SS + s] = o;
            }
    }
}

// ------------- flash attention (causal): wave = 32 q-rows, kb/vb register reuse -------------
// Block = 4 waves = 128 q-rows of one head. K/V double-buffered LDS (swizzled),
// swapped QK^T lane-local softmax in exp2 domain, cvt_pk P-pack, defer-max 11.5 (log2).
__global__ __launch_bounds__(256, 3) void attn_kernel(const short* __restrict__ Q,
                                                      const short* __restrict__ K,
                                                      const short* __restrict__ Vt,
                                                      short* __restrict__ ctx) {
    __shared__ __align__(16) short Ks[2][64 * 64];
    __shared__ __align__(16) short Vs[2][64 * 64];
    __shared__ __align__(16) short pl[4][2][16][72];
    int tid = threadIdx.x;
    int wv = tid >> 6, lane = tid & 63;
    int m = lane & 15, g = lane >> 4;
    int bid = blockIdx.x;
    int qblk = 15 - (bid >> 5);         // heavy-first
    int bh = bid & 31;
    int b = bh >> 4, h = bh & 15;
    const short* Qb = Q + (size_t)bh * SS * EE;
    const short* Kb = K + (size_t)bh * SS * EE;
    const short* Vb = Vt + (size_t)bh * EE * SS;
    int qr0 = qblk * 128 + wv * 32 + m;
    int qr1 = qr0 + 16;

    int srow = wv * 8 + (lane >> 3);
    int scol_s = (((lane & 7) * 16) ^ ((srow & 7) << 4)) >> 1;

    bf16x8 qa00 = *(const bf16x8*)(Qb + (size_t)qr0 * EE + g * 8);
    bf16x8 qa01 = *(const bf16x8*)(Qb + (size_t)qr0 * EE + 32 + g * 8);
    bf16x8 qa10 = *(const bf16x8*)(Qb + (size_t)qr1 * EE + g * 8);
    bf16x8 qa11 = *(const bf16x8*)(Qb + (size_t)qr1 * EE + 32 + g * 8);

    int sw = (m & 7) << 4;
    int c0 = (g * 16) ^ sw;
    int c1 = (64 + g * 16) ^ sw;

    float mreg0 = -INFINITY, lsum0 = 0.f, mreg1 = -INFINITY, lsum1 = 0.f;
    f32x4 o0[4], o1[4];
#pragma unroll
    for (int n = 0; n < 4; ++n) {
        o0[n][0] = 0.f; o0[n][1] = 0.f; o0[n][2] = 0.f; o0[n][3] = 0.f;
        o1[n][0] = 0.f; o1[n][1] = 0.f; o1[n][2] = 0.f; o1[n][3] = 0.f;
    }

    auto STAGE = [&](int nb, int t0) {
        short* kd = &Ks[0][0] + nb * 4096 + wv * 512;
        short* vd = &Vs[0][0] + nb * 4096 + wv * 512;
        const short* ksrc = Kb + (size_t)(t0 + srow) * EE + scol_s;
        const short* vsrc = Vb + (size_t)srow * SS + t0 + scol_s;
        GLDS(ksrc, kd);
        GLDS(ksrc + 32 * EE, kd + 2048);
        GLDS(vsrc, vd);
        GLDS(vsrc + (size_t)32 * SS, vd + 2048);
    };

    // softmax for one subtile: in-place exp2, cvt_pk pack into pls
    auto SOFTMAX = [&](f32x4 (&s)[4], float& mreg, float& lsum, f32x4 (&o)[4], short (*pls)[72]) {
        float mx = s[0][0];
#pragma unroll
        for (int n = 0; n < 4; ++n)
#pragma unroll
            for (int r = 0; r < 4; ++r) mx = fmaxf(mx, s[n][r]);
        mx = fmaxf(mx, __shfl_xor(mx, 16, 64));
        mx = fmaxf(mx, __shfl_xor(mx, 32, 64));
        if (!__all(mx <= mreg + 11.5f)) {      // defer-max, log2 units
            float mn = fmaxf(mreg, mx);
            float al = exp2f(mreg - mn);
            lsum *= al;
#pragma unroll
            for (int n = 0; n < 4; ++n)
#pragma unroll
                for (int r = 0; r < 4; ++r) o[n][r] *= al;
            mreg = mn;
        }
#pragma unroll
        for (int n = 0; n < 4; ++n) {
            float p0 = exp2f(s[n][0] - mreg);
            float p1 = exp2f(s[n][1] - mreg);
            float p2 = exp2f(s[n][2] - mreg);
            float p3 = exp2f(s[n][3] - mreg);
            lsum += (p0 + p1) + (p2 + p3);
            u32x2 pk; pk[0] = cvtpk(p0, p1); pk[1] = cvtpk(p2, p3);
            *(u32x2*)&pls[m][n * 16 + g * 4] = pk;
        }
    };

    int ntile = 2 * qblk + 2;
    STAGE(0, 0);
    __syncthreads();

    for (int tt = 0; tt < ntile; ++tt) {
        if (tt + 1 < ntile) STAGE((tt + 1) & 1, (tt + 1) * 64);
        int t0 = tt * 64;
        const short* Ksb = &Ks[0][0] + (tt & 1) * 4096;
        const short* Vsb = &Vs[0][0] + (tt & 1) * 4096;

        // QK^T for both subtiles, kb fragments shared
        f32x4 s0[4], s1[4];
#pragma unroll
        for (int n = 0; n < 4; ++n) {
            s0[n] = {0, 0, 0, 0}; s1[n] = {0, 0, 0, 0};
            const char* krow = (const char*)(Ksb + (n * 16 + m) * 64);
            bf16x8 kb0 = *(const bf16x8*)(krow + c0);
            bf16x8 kb1 = *(const bf16x8*)(krow + c1);
            s0[n] = __builtin_amdgcn_mfma_f32_16x16x32_bf16(kb0, qa00, s0[n], 0, 0, 0);
            s0[n] = __builtin_amdgcn_mfma_f32_16x16x32_bf16(kb1, qa01, s0[n], 0, 0, 0);
            s1[n] = __builtin_amdgcn_mfma_f32_16x16x32_bf16(kb0, qa10, s1[n], 0, 0, 0);
            s1[n] = __builtin_amdgcn_mfma_f32_16x16x32_bf16(kb1, qa11, s1[n], 0, 0, 0);
        }

        // causal mask (wave-uniform outer branch per subtile)
        if (t0 + 63 > qblk * 128 + wv * 32) {
#pragma unroll
            for (int n = 0; n < 4; ++n)
#pragma unroll
                for (int r = 0; r < 4; ++r)
                    if (t0 + n * 16 + g * 4 + r > qr0) s0[n][r] = -INFINITY;
        }
        if (t0 + 63 > qblk * 128 + wv * 32 + 16) {
#pragma unroll
            for (int n = 0; n < 4; ++n)
#pragma unroll
                for (int r = 0; r < 4; ++r)
                    if (t0 + n * 16 + g * 4 + r > qr1) s1[n][r] = -INFINITY;
        }

        SOFTMAX(s0, mreg0, lsum0, o0, pl[wv][0]);
        SOFTMAX(s1, mreg1, lsum1, o1, pl[wv][1]);

        // PV: vb fragments shared across both subtiles
#pragma unroll
        for (int ks = 0; ks < 2; ++ks) {
            bf16x8 pa0 = *(const bf16x8*)&pl[wv][0][m][ks * 32 + g * 8];
            bf16x8 pa1 = *(const bf16x8*)&pl[wv][1][m][ks * 32 + g * 8];
            int cv = ks ? c1 : c0;
#pragma unroll
            for (int n = 0; n < 4; ++n) {
                const char* vrow = (const char*)(Vsb + (n * 16 + m) * 64);
                bf16x8 vb = *(const bf16x8*)(vrow + cv);
                o0[n] = __builtin_amdgcn_mfma_f32_16x16x32_bf16(vb, pa0, o0[n], 0, 0, 0);
                o1[n] = __builtin_amdgcn_mfma_f32_16x16x32_bf16(vb, pa1, o1[n], 0, 0, 0);
            }
        }

        __syncthreads();
    }

    lsum0 += __shfl_xor(lsum0, 16, 64);
    lsum0 += __shfl_xor(lsum0, 32, 64);
    lsum1 += __shfl_xor(lsum1, 16, 64);
    lsum1 += __shfl_xor(lsum1, 32, 64);
    float inv0 = 1.0f / lsum0;
    float inv1 = 1.0f / lsum1;
    short* cb0 = ctx + (size_t)(b * SS + qr0) * (HH * EE) + h * EE;
    short* cb1 = ctx + (size_t)(b * SS + qr1) * (HH * EE) + h * EE;
#pragma unroll
    for (int n = 0; n < 4; ++n) {
        u32x2 k0; k0[0] = cvtpk(o0[n][0] * inv0, o0[n][1] * inv0);
        k0[1] = cvtpk(o0[n][2] * inv0, o0[n][3] * inv0);
        *(u32x2*)&cb0[n * 16 + g * 4] = k0;
        u32x2 k1; k1[0] = cvtpk(o1[n][0] * inv1, o1[n][1] * inv1);
        k1[1] = cvtpk(o1[n][2] * inv1, o1[n][3] * inv1);
        *(u32x2*)&cb1[n * 16 + g * 4] = k1;
    }
}

// ------------- output projection: ctx [4096,1024] @ W [1024,64] -> out fp32 -------------
__global__ __launch_bounds__(256) void outproj_kernel(const short* __restrict__ ctx,
                                                      const short* __restrict__ wot,
                                                      float* __restrict__ out) {
    __shared__ float red[4][1024];
    int wv = threadIdx.x >> 6, lane = threadIdx.x & 63;
    int m = lane & 15, g = lane >> 4;
    int r0 = blockIdx.x * 16;
    const short* arow = ctx + (size_t)(r0 + m) * (HH * EE) + g * 8;
    const short* wb = wot + g * 8;
    f32x4 acc[4] = {{0,0,0,0},{0,0,0,0},{0,0,0,0},{0,0,0,0}};
    int k0 = wv * 256;
    for (int d0 = k0; d0 < k0 + 256; d0 += 32) {
        bf16x8 a = *(const bf16x8*)(arow + d0);
#pragma unroll
        for (int n = 0; n < 4; ++n) {
            bf16x8 bbf = *(const bf16x8*)(wb + (size_t)(n * 16 + m) * (HH * EE) + d0);
            acc[n] = __builtin_amdgcn_mfma_f32_16x16x32_bf16(a, bbf, acc[n], 0, 0, 0);
        }
    }
#pragma unroll
    for (int n = 0; n < 4; ++n)
#pragma unroll
        for (int r = 0; r < 4; ++r)
            red[wv][(g * 4 + r) * 64 + n * 16 + m] = acc[n][r];
    __syncthreads();
    int t = threadIdx.x;
    float4v sum = ((const float4v*)red[0])[t];
    sum += ((const float4v*)red[1])[t];
    sum += ((const float4v*)red[2])[t];
    sum += ((const float4v*)red[3])[t];
    ((float4v*)(out + (size_t)blockIdx.x * 1024))[t] = sum;
}

extern "C" void kernel_launch(void* const* d_in, const int* in_sizes, int n_in,
                              void* d_out, int out_size, void* d_ws, size_t ws_size,
                              hipStream_t stream) {
    const float* x  = (const float*)d_in[0];
    const float* Wq = (const float*)d_in[1];
    const float* Wk = (const float*)d_in[2];
    const float* Wv = (const float*)d_in[3];
    const float* W  = (const float*)d_in[4];
    float* out = (float*)d_out;

    char* w = (char*)d_ws;
    short* xb  = (short*)w;                                   // 8 MB
    short* wqt = (short*)(w + ((size_t)8 << 20));             // 2 MB each, contiguous = Bt
    short* wkt = wqt + (size_t)HH * EE * DD;
    short* wvt = wkt + (size_t)HH * EE * DD;
    short* wot = wvt + (size_t)HH * EE * DD;                  // 128 KB
    short* Qb  = wot + (size_t)64 * 1024;                     // 8 MB each
    short* Kb  = Qb + (size_t)BB * HH * SS * EE;
    short* Vtb = Kb + (size_t)BB * HH * SS * EE;
    short* ctx = Vtb + (size_t)BB * HH * SS * EE;             // 8 MB

    int n4 = BB * SS * DD / 4;
    convert_x_kernel<<<n4 / 256, 256, 0, stream>>>(x, xb, n4);
    transpose_w3_kernel<<<dim3(16, 48), 256, 0, stream>>>(Wq, Wk, Wv, wqt);
    transpose_w_kernel<<<dim3(16, 1), 256, 0, stream>>>(W, wot, HH * EE);

    qkv_gemm<<<192, 512, 0, stream>>>(xb, wqt, Qb, Kb, Vtb);
    attn_kernel<<<512, 256, 0, stream>>>(Qb, Kb, Vtb, ctx);
    outproj_kernel<<<256, 256, 0, stream>>>(ctx, wot, out);
}

// Round 9
// 110.007 us; speedup vs baseline: 1.1474x; 1.1474x over previous
//
#include <hip/hip_runtime.h>
#include <hip/hip_bf16.h>
#include <cstdint>
#include <cstddef>

#define BB 2
#define SS 2048
#define DD 1024
#define HH 16
#define EE 64

typedef short bf16x8 __attribute__((ext_vector_type(8)));
typedef short s4 __attribute__((ext_vector_type(4)));
typedef float f32x4 __attribute__((ext_vector_type(4)));
typedef float float4v __attribute__((ext_vector_type(4)));
typedef unsigned int u32x2 __attribute__((ext_vector_type(2)));

#define GLDS(gp, lp) __builtin_amdgcn_global_load_lds( \
    (const __attribute__((address_space(1))) void*)(gp), \
    (__attribute__((address_space(3))) void*)(lp), 16, 0, 0)

static __device__ __forceinline__ short f2bf(float f) {
    union { float f; uint32_t u; } v; v.f = f;
    uint32_t r = (v.u + 0x7fffu + ((v.u >> 16) & 1u)) >> 16;
    return (short)r;
}

// packed f32x2 -> bf16x2 (RNE), single HW op
static __device__ __forceinline__ uint32_t cvtpk(float a, float b) {
    uint32_t r;
    asm("v_cvt_pk_bf16_f32 %0, %1, %2" : "=v"(r) : "v"(a), "v"(b));
    return r;
}

// ---------------- fp32 -> bf16 convert (vectorized) ----------------
__global__ void convert_x_kernel(const float* __restrict__ x, short* __restrict__ xb, int n4) {
    int i = blockIdx.x * blockDim.x + threadIdx.x;
    if (i >= n4) return;
    float4v v = ((const float4v*)x)[i];
    s4 o; o[0] = f2bf(v[0]); o[1] = f2bf(v[1]); o[2] = f2bf(v[2]); o[3] = f2bf(v[3]);
    ((s4*)xb)[i] = o;
}

// ------------- weight transpose+convert: 3x [16][1024 x 64] -> [16][64 x 1024] bf16 -------------
__global__ void transpose_w3_kernel(const float* __restrict__ Wq,
                                    const float* __restrict__ Wk,
                                    const float* __restrict__ Wv,
                                    short* __restrict__ dst) {
    __shared__ float tile[64][65];
    int which = blockIdx.y >> 4;
    int mtx = blockIdx.y & 15;
    const float* src = (which == 0) ? Wq : (which == 1) ? Wk : Wv;
    int r0 = blockIdx.x * 64;
    const float* s = src + (size_t)mtx * DD * 64;
    short* d = dst + (size_t)which * HH * EE * DD + (size_t)mtx * DD * 64;
    int t = threadIdx.x;
#pragma unroll
    for (int i = 0; i < 16; ++i) {
        int idx = t + i * 256;
        int r = idx >> 6, c = idx & 63;
        tile[r][c] = s[(size_t)(r0 + r) * 64 + c];
    }
    __syncthreads();
#pragma unroll
    for (int i = 0; i < 16; ++i) {
        int idx = t + i * 256;
        int e = idx >> 6, dd2 = idx & 63;
        d[(size_t)e * DD + r0 + dd2] = f2bf(tile[dd2][e]);
    }
}

__global__ void transpose_w_kernel(const float* __restrict__ src, short* __restrict__ dst, int R) {
    __shared__ float tile[64][65];
    int r0 = blockIdx.x * 64;
    int t = threadIdx.x;
#pragma unroll
    for (int i = 0; i < 16; ++i) {
        int idx = t + i * 256;
        int r = idx >> 6, c = idx & 63;
        tile[r][c] = src[(size_t)(r0 + r) * 64 + c];
    }
    __syncthreads();
#pragma unroll
    for (int i = 0; i < 16; ++i) {
        int idx = t + i * 256;
        int e = idx >> 6, dd2 = idx & 63;
        dst[(size_t)e * R + r0 + dd2] = f2bf(tile[dd2][e]);
    }
}

// ------------- QKV GEMM: 256x256 tile, BK=32, 8 waves, triple-buffer, counted vmcnt -------------
__global__ __launch_bounds__(512, 2) void qkv_gemm(const short* __restrict__ A,
                                                   const short* __restrict__ Bt,
                                                   short* __restrict__ Qo,
                                                   short* __restrict__ Ko,
                                                   short* __restrict__ Vto) {
    __shared__ __align__(16) short As3[3][128 * 64];
    __shared__ __align__(16) short Bs3[3][128 * 64];
    int tid = threadIdx.x;
    int wv = tid >> 6, lane = tid & 63;
    int m = lane & 15, g = lane >> 4;
    int wr = wv >> 2, wc = wv & 3;

    int xcd = blockIdx.x & 7, idx = blockIdx.x >> 3;
    int mb = (xcd & 3) * 4 + (idx & 3);
    int nb = (xcd >> 2) * 6 + (idx >> 2);
    int rowBase = mb * 256, colBase0 = nb * 256;

    int src_row[2], src_kcol[2];
#pragma unroll
    for (int j = 0; j < 2; ++j) {
        int si = j * 512 + tid;
        int sr = si >> 3, sp = si & 7;
        int sl = sp ^ (sr & 7);
        src_row[j] = 2 * sr + (sl >> 2);
        src_kcol[j] = (sl & 3) * 8;
    }
    const short* aP0 = A + (size_t)(rowBase + src_row[0]) * DD + src_kcol[0];
    const short* aP1 = A + (size_t)(rowBase + src_row[1]) * DD + src_kcol[1];
    const short* bP0 = Bt + (size_t)(colBase0 + src_row[0]) * DD + src_kcol[0];
    const short* bP1 = Bt + (size_t)(colBase0 + src_row[1]) * DD + src_kcol[1];
    int dst0 = (wv * 64) * 8;
    int dst1 = (512 + wv * 64) * 8;

    f32x4 acc[8][4];
#pragma unroll
    for (int i = 0; i < 8; ++i)
#pragma unroll
        for (int j = 0; j < 4; ++j) acc[i][j] = {0, 0, 0, 0};

    int rdoff = ((m & 1) * 64 + g * 16) ^ (((m >> 1) & 7) << 4);
    int mh = m >> 1;

    auto STAGE = [&](int buf, int kt) {
        short* ab = &As3[buf][0];
        short* bb = &Bs3[buf][0];
        GLDS(aP0 + kt, ab + dst0);
        GLDS(aP1 + kt, ab + dst1);
        GLDS(bP0 + kt, bb + dst0);
        GLDS(bP1 + kt, bb + dst1);
    };

    auto COMPUTE = [&](int buf) {
        bf16x8 af[8], bfr[4];
#pragma unroll
        for (int mi = 0; mi < 8; ++mi)
            af[mi] = *(const bf16x8*)((const char*)&As3[buf][(wr * 64 + mi * 8 + mh) * 64] + rdoff);
#pragma unroll
        for (int ni = 0; ni < 4; ++ni)
            bfr[ni] = *(const bf16x8*)((const char*)&Bs3[buf][(wc * 32 + ni * 8 + mh) * 64] + rdoff);
        asm volatile("s_waitcnt lgkmcnt(0)\ns_barrier" ::: "memory");
        __builtin_amdgcn_s_setprio(1);
#pragma unroll
        for (int mi = 0; mi < 8; ++mi)
#pragma unroll
            for (int ni = 0; ni < 4; ++ni)
                acc[mi][ni] = __builtin_amdgcn_mfma_f32_16x16x32_bf16(af[mi], bfr[ni], acc[mi][ni], 0, 0, 0);
        __builtin_amdgcn_s_setprio(0);
    };

    STAGE(0, 0);
    STAGE(1, 32);
    for (int t = 0; t < 30; ++t) {
        STAGE((t + 2) % 3, (t + 2) * 32);
        asm volatile("s_waitcnt vmcnt(8)\ns_barrier" ::: "memory");
        COMPUTE(t % 3);
    }
    asm volatile("s_waitcnt vmcnt(4)\ns_barrier" ::: "memory");
    COMPUTE(0);
    asm volatile("s_waitcnt vmcnt(0)\ns_barrier" ::: "memory");
    COMPUTE(1);

    int colw = colBase0 + wc * 64;
    int mtx = colw >> 10;
    int h = (colw >> 6) & 15;
    int rb = rowBase + wr * 128;

    if (mtx == 0) {
        // Q pre-scaled by 1/8 * log2(e) so attention can use exp2 directly
        const float qs = 0.125f * 1.44269504089f;
#pragma unroll
        for (int mi = 0; mi < 8; ++mi)
#pragma unroll
            for (int ni = 0; ni < 4; ++ni)
#pragma unroll
                for (int r = 0; r < 4; ++r) {
                    int row = rb + mi * 16 + g * 4 + r;
                    int b = row >> 11, s = row & 2047;
                    Qo[((size_t)(b * HH + h) * SS + s) * EE + ni * 16 + m] = f2bf(acc[mi][ni][r] * qs);
                }
    } else if (mtx == 1) {
#pragma unroll
        for (int mi = 0; mi < 8; ++mi)
#pragma unroll
            for (int ni = 0; ni < 4; ++ni)
#pragma unroll
                for (int r = 0; r < 4; ++r) {
                    int row = rb + mi * 16 + g * 4 + r;
                    int b = row >> 11, s = row & 2047;
                    Ko[((size_t)(b * HH + h) * SS + s) * EE + ni * 16 + m] = f2bf(acc[mi][ni][r]);
                }
    } else {
#pragma unroll
        for (int mi = 0; mi < 8; ++mi)
#pragma unroll
            for (int ni = 0; ni < 4; ++ni) {
                int row0 = rb + mi * 16 + g * 4;
                int b = row0 >> 11, s = row0 & 2047;
                s4 o; o[0] = f2bf(acc[mi][ni][0]); o[1] = f2bf(acc[mi][ni][1]);
                o[2] = f2bf(acc[mi][ni][2]); o[3] = f2bf(acc[mi][ni][3]);
                *(s4*)&Vto[((size_t)(b * HH + h) * EE + ni * 16 + m) * SS + s] = o;
            }
    }
}

// ------------- flash attention (causal): r7 structure + exp2/cvt_pk VALU cuts -------------
// Block = 4 waves = 64 q-rows of one head; 1024 blocks heavy-first.
// K/V double-buffered LDS (XOR-swizzled both sides), swapped QK^T lane-local
// softmax in exp2 domain, cvt_pk P-pack, defer-max 11.5 log2-units.
__global__ __launch_bounds__(256, 3) void attn_kernel(const short* __restrict__ Q,
                                                      const short* __restrict__ K,
                                                      const short* __restrict__ Vt,
                                                      short* __restrict__ ctx) {
    __shared__ __align__(16) short Ks[2][64 * 64];
    __shared__ __align__(16) short Vs[2][64 * 64];
    __shared__ __align__(16) short pl[4][16][72];
    int tid = threadIdx.x;
    int wv = tid >> 6, lane = tid & 63;
    int m = lane & 15, g = lane >> 4;
    int bid = blockIdx.x;
    int qblk = 31 - (bid >> 5);         // heavy-first
    int bh = bid & 31;
    int b = bh >> 4, h = bh & 15;
    const short* Qb = Q + (size_t)bh * SS * EE;
    const short* Kb = K + (size_t)bh * SS * EE;
    const short* Vb = Vt + (size_t)bh * EE * SS;
    int qrow = qblk * 64 + wv * 16 + m;

    int srow = wv * 8 + (lane >> 3);
    int scol_s = (((lane & 7) * 16) ^ ((srow & 7) << 4)) >> 1;

    bf16x8 qa0 = *(const bf16x8*)(Qb + (size_t)qrow * EE + g * 8);
    bf16x8 qa1 = *(const bf16x8*)(Qb + (size_t)qrow * EE + 32 + g * 8);

    int sw = (m & 7) << 4;
    int c0 = (g * 16) ^ sw;
    int c1 = (64 + g * 16) ^ sw;

    float mreg = -INFINITY, lsum = 0.f;
    f32x4 o[4];
#pragma unroll
    for (int n = 0; n < 4; ++n) { o[n][0] = 0.f; o[n][1] = 0.f; o[n][2] = 0.f; o[n][3] = 0.f; }

    auto STAGE = [&](int nb, int t0) {
        short* kd = &Ks[0][0] + nb * 4096 + wv * 512;
        short* vd = &Vs[0][0] + nb * 4096 + wv * 512;
        const short* ksrc = Kb + (size_t)(t0 + srow) * EE + scol_s;
        const short* vsrc = Vb + (size_t)srow * SS + t0 + scol_s;
        GLDS(ksrc, kd);
        GLDS(ksrc + 32 * EE, kd + 2048);
        GLDS(vsrc, vd);
        GLDS(vsrc + (size_t)32 * SS, vd + 2048);
    };

    int ntile = qblk + 1;
    STAGE(0, 0);
    __syncthreads();

    for (int tt = 0; tt < ntile; ++tt) {
        if (tt + 1 < ntile) STAGE((tt + 1) & 1, (tt + 1) * 64);
        int t0 = tt * 64;
        const short* Ksb = &Ks[0][0] + (tt & 1) * 4096;
        const short* Vsb = &Vs[0][0] + (tt & 1) * 4096;

        // S^T = K x Q (scores already in log2 domain via Q pre-scale)
        f32x4 s[4] = {{0,0,0,0},{0,0,0,0},{0,0,0,0},{0,0,0,0}};
#pragma unroll
        for (int n = 0; n < 4; ++n) {
            const char* krow = (const char*)(Ksb + (n * 16 + m) * 64);
            bf16x8 kb0 = *(const bf16x8*)(krow + c0);
            s[n] = __builtin_amdgcn_mfma_f32_16x16x32_bf16(kb0, qa0, s[n], 0, 0, 0);
            bf16x8 kb1 = *(const bf16x8*)(krow + c1);
            s[n] = __builtin_amdgcn_mfma_f32_16x16x32_bf16(kb1, qa1, s[n], 0, 0, 0);
        }

        if (tt == qblk) {
#pragma unroll
            for (int n = 0; n < 4; ++n)
#pragma unroll
                for (int r = 0; r < 4; ++r)
                    if (t0 + n * 16 + g * 4 + r > qrow) s[n][r] = -INFINITY;
        }

        // row max: 15 in-lane fmax + 2 shuffles
        float mx = s[0][0];
#pragma unroll
        for (int n = 0; n < 4; ++n)
#pragma unroll
            for (int r = 0; r < 4; ++r) mx = fmaxf(mx, s[n][r]);
        mx = fmaxf(mx, __shfl_xor(mx, 16, 64));
        mx = fmaxf(mx, __shfl_xor(mx, 32, 64));

        // defer-max (11.5 log2-units ~ 8 nats)
        if (!__all(mx <= mreg + 11.5f)) {
            float mn = fmaxf(mreg, mx);
            float al = exp2f(mreg - mn);
            lsum *= al;
#pragma unroll
            for (int n = 0; n < 4; ++n)
#pragma unroll
                for (int r = 0; r < 4; ++r) o[n][r] *= al;
            mreg = mn;
        }

        // exp2 + partial sum + cvt_pk P pack to LDS
#pragma unroll
        for (int n = 0; n < 4; ++n) {
            float p0 = exp2f(s[n][0] - mreg);
            float p1 = exp2f(s[n][1] - mreg);
            float p2 = exp2f(s[n][2] - mreg);
            float p3 = exp2f(s[n][3] - mreg);
            lsum += (p0 + p1) + (p2 + p3);
            u32x2 pk; pk[0] = cvtpk(p0, p1); pk[1] = cvtpk(p2, p3);
            *(u32x2*)&pl[wv][m][n * 16 + g * 4] = pk;
        }

        // PV: o^T += V^T x P
#pragma unroll
        for (int ks = 0; ks < 2; ++ks) {
            bf16x8 pa = *(const bf16x8*)&pl[wv][m][ks * 32 + g * 8];
            int cv = ks ? c1 : c0;
#pragma unroll
            for (int n = 0; n < 4; ++n) {
                const char* vrow = (const char*)(Vsb + (n * 16 + m) * 64);
                bf16x8 vb = *(const bf16x8*)(vrow + cv);
                o[n] = __builtin_amdgcn_mfma_f32_16x16x32_bf16(vb, pa, o[n], 0, 0, 0);
            }
        }

        __syncthreads();
    }

    lsum += __shfl_xor(lsum, 16, 64);
    lsum += __shfl_xor(lsum, 32, 64);
    float inv = 1.0f / lsum;
    short* cb = ctx + (size_t)(b * SS + qrow) * (HH * EE) + h * EE;
#pragma unroll
    for (int n = 0; n < 4; ++n) {
        u32x2 k0; k0[0] = cvtpk(o[n][0] * inv, o[n][1] * inv);
        k0[1] = cvtpk(o[n][2] * inv, o[n][3] * inv);
        *(u32x2*)&cb[n * 16 + g * 4] = k0;
    }
}

// ------------- output projection: ctx [4096,1024] @ W [1024,64] -> out fp32 -------------
__global__ __launch_bounds__(256) void outproj_kernel(const short* __restrict__ ctx,
                                                      const short* __restrict__ wot,
                                                      float* __restrict__ out) {
    __shared__ float red[4][1024];
    int wv = threadIdx.x >> 6, lane = threadIdx.x & 63;
    int m = lane & 15, g = lane >> 4;
    int r0 = blockIdx.x * 16;
    const short* arow = ctx + (size_t)(r0 + m) * (HH * EE) + g * 8;
    const short* wb = wot + g * 8;
    f32x4 acc[4] = {{0,0,0,0},{0,0,0,0},{0,0,0,0},{0,0,0,0}};
    int k0 = wv * 256;
    for (int d0 = k0; d0 < k0 + 256; d0 += 32) {
        bf16x8 a = *(const bf16x8*)(arow + d0);
#pragma unroll
        for (int n = 0; n < 4; ++n) {
            bf16x8 bbf = *(const bf16x8*)(wb + (size_t)(n * 16 + m) * (HH * EE) + d0);
            acc[n] = __builtin_amdgcn_mfma_f32_16x16x32_bf16(a, bbf, acc[n], 0, 0, 0);
        }
    }
#pragma unroll
    for (int n = 0; n < 4; ++n)
#pragma unroll
        for (int r = 0; r < 4; ++r)
            red[wv][(g * 4 + r) * 64 + n * 16 + m] = acc[n][r];
    __syncthreads();
    int t = threadIdx.x;
    float4v sum = ((const float4v*)red[0])[t];
    sum += ((const float4v*)red[1])[t];
    sum += ((const float4v*)red[2])[t];
    sum += ((const float4v*)red[3])[t];
    ((float4v*)(out + (size_t)blockIdx.x * 1024))[t] = sum;
}

extern "C" void kernel_launch(void* const* d_in, const int* in_sizes, int n_in,
                              void* d_out, int out_size, void* d_ws, size_t ws_size,
                              hipStream_t stream) {
    const float* x  = (const float*)d_in[0];
    const float* Wq = (const float*)d_in[1];
    const float* Wk = (const float*)d_in[2];
    const float* Wv = (const float*)d_in[3];
    const float* W  = (const float*)d_in[4];
    float* out = (float*)d_out;

    char* w = (char*)d_ws;
    short* xb  = (short*)w;                                   // 8 MB
    short* wqt = (short*)(w + ((size_t)8 << 20));             // 2 MB each, contiguous = Bt
    short* wkt = wqt + (size_t)HH * EE * DD;
    short* wvt = wkt + (size_t)HH * EE * DD;
    short* wot = wvt + (size_t)HH * EE * DD;                  // 128 KB
    short* Qb  = wot + (size_t)64 * 1024;                     // 8 MB each
    short* Kb  = Qb + (size_t)BB * HH * SS * EE;
    short* Vtb = Kb + (size_t)BB * HH * SS * EE;
    short* ctx = Vtb + (size_t)BB * HH * SS * EE;             // 8 MB

    int n4 = BB * SS * DD / 4;
    convert_x_kernel<<<n4 / 256, 256, 0, stream>>>(x, xb, n4);
    transpose_w3_kernel<<<dim3(16, 48), 256, 0, stream>>>(Wq, Wk, Wv, wqt);
    transpose_w_kernel<<<dim3(16, 1), 256, 0, stream>>>(W, wot, HH * EE);

    qkv_gemm<<<192, 512, 0, stream>>>(xb, wqt, Qb, Kb, Vtb);
    attn_kernel<<<1024, 256, 0, stream>>>(Qb, Kb, Vtb, ctx);
    outproj_kernel<<<256, 256, 0, stream>>>(ctx, wot, out);
}

// Round 10
// 108.205 us; speedup vs baseline: 1.1665x; 1.0167x over previous
//
#include <hip/hip_runtime.h>
#include <hip/hip_bf16.h>
#include <cstdint>
#include <cstddef>

#define BB 2
#define SS 2048
#define DD 1024
#define HH 16
#define EE 64

typedef short bf16x8 __attribute__((ext_vector_type(8)));
typedef short s4 __attribute__((ext_vector_type(4)));
typedef float f32x4 __attribute__((ext_vector_type(4)));
typedef float float4v __attribute__((ext_vector_type(4)));
typedef unsigned int u32x2 __attribute__((ext_vector_type(2)));

#define GLDS(gp, lp) __builtin_amdgcn_global_load_lds( \
    (const __attribute__((address_space(1))) void*)(gp), \
    (__attribute__((address_space(3))) void*)(lp), 16, 0, 0)

static __device__ __forceinline__ short f2bf(float f) {
    union { float f; uint32_t u; } v; v.f = f;
    uint32_t r = (v.u + 0x7fffu + ((v.u >> 16) & 1u)) >> 16;
    return (short)r;
}

// packed f32x2 -> bf16x2 (RNE), single HW op
static __device__ __forceinline__ uint32_t cvtpk(float a, float b) {
    uint32_t r;
    asm("v_cvt_pk_bf16_f32 %0, %1, %2" : "=v"(r) : "v"(a), "v"(b));
    return r;
}

// ------------- fused prep: x convert (blocks 0..4095), W transposes (4096..4879) -------------
__global__ __launch_bounds__(256) void prep_kernel(const float* __restrict__ x,
                                                   const float* __restrict__ Wq,
                                                   const float* __restrict__ Wk,
                                                   const float* __restrict__ Wv,
                                                   const float* __restrict__ W,
                                                   short* __restrict__ xb,
                                                   short* __restrict__ wt,
                                                   short* __restrict__ wot) {
    __shared__ float tile[64][65];
    int blk = blockIdx.x;
    int t = threadIdx.x;
    if (blk < 4096) {
        int i = blk * 256 + t;      // n4 = 1048576 = 4096*256 exactly
        float4v v = ((const float4v*)x)[i];
        s4 o; o[0] = f2bf(v[0]); o[1] = f2bf(v[1]); o[2] = f2bf(v[2]); o[3] = f2bf(v[3]);
        ((s4*)xb)[i] = o;
        return;
    }
    int idx = blk - 4096;
    const float* src;
    short* d;
    int R, r0;
    if (idx < 768) {
        int bx = idx & 15, by = idx >> 4;
        int which = by >> 4, mtx = by & 15;
        src = ((which == 0) ? Wq : (which == 1) ? Wk : Wv) + (size_t)mtx * DD * 64;
        d = wt + (size_t)which * HH * EE * DD + (size_t)mtx * DD * 64;
        R = DD; r0 = bx * 64;
    } else {
        int bx = idx - 768;
        src = W; d = wot; R = HH * EE; r0 = bx * 64;
    }
#pragma unroll
    for (int i = 0; i < 16; ++i) {
        int id2 = t + i * 256;
        int r = id2 >> 6, c = id2 & 63;
        tile[r][c] = src[(size_t)(r0 + r) * 64 + c];
    }
    __syncthreads();
#pragma unroll
    for (int i = 0; i < 16; ++i) {
        int id2 = t + i * 256;
        int e = id2 >> 6, dd2 = id2 & 63;
        d[(size_t)e * R + r0 + dd2] = f2bf(tile[dd2][e]);
    }
}

// ------------- QKV GEMM: 256x256 tile, BK=32, 8 waves, triple-buffer, counted vmcnt -------------
__global__ __launch_bounds__(512, 2) void qkv_gemm(const short* __restrict__ A,
                                                   const short* __restrict__ Bt,
                                                   short* __restrict__ Qo,
                                                   short* __restrict__ Ko,
                                                   short* __restrict__ Vto) {
    __shared__ __align__(16) short As3[3][128 * 64];
    __shared__ __align__(16) short Bs3[3][128 * 64];
    int tid = threadIdx.x;
    int wv = tid >> 6, lane = tid & 63;
    int m = lane & 15, g = lane >> 4;
    int wr = wv >> 2, wc = wv & 3;

    int xcd = blockIdx.x & 7, idx = blockIdx.x >> 3;
    int mb = (xcd & 3) * 4 + (idx & 3);
    int nb = (xcd >> 2) * 6 + (idx >> 2);
    int rowBase = mb * 256, colBase0 = nb * 256;

    int src_row[2], src_kcol[2];
#pragma unroll
    for (int j = 0; j < 2; ++j) {
        int si = j * 512 + tid;
        int sr = si >> 3, sp = si & 7;
        int sl = sp ^ (sr & 7);
        src_row[j] = 2 * sr + (sl >> 2);
        src_kcol[j] = (sl & 3) * 8;
    }
    const short* aP0 = A + (size_t)(rowBase + src_row[0]) * DD + src_kcol[0];
    const short* aP1 = A + (size_t)(rowBase + src_row[1]) * DD + src_kcol[1];
    const short* bP0 = Bt + (size_t)(colBase0 + src_row[0]) * DD + src_kcol[0];
    const short* bP1 = Bt + (size_t)(colBase0 + src_row[1]) * DD + src_kcol[1];
    int dst0 = (wv * 64) * 8;
    int dst1 = (512 + wv * 64) * 8;

    f32x4 acc[8][4];
#pragma unroll
    for (int i = 0; i < 8; ++i)
#pragma unroll
        for (int j = 0; j < 4; ++j) acc[i][j] = {0, 0, 0, 0};

    int rdoff = ((m & 1) * 64 + g * 16) ^ (((m >> 1) & 7) << 4);
    int mh = m >> 1;

    auto STAGE = [&](int buf, int kt) {
        short* ab = &As3[buf][0];
        short* bb = &Bs3[buf][0];
        GLDS(aP0 + kt, ab + dst0);
        GLDS(aP1 + kt, ab + dst1);
        GLDS(bP0 + kt, bb + dst0);
        GLDS(bP1 + kt, bb + dst1);
    };

    auto COMPUTE = [&](int buf) {
        bf16x8 af[8], bfr[4];
#pragma unroll
        for (int mi = 0; mi < 8; ++mi)
            af[mi] = *(const bf16x8*)((const char*)&As3[buf][(wr * 64 + mi * 8 + mh) * 64] + rdoff);
#pragma unroll
        for (int ni = 0; ni < 4; ++ni)
            bfr[ni] = *(const bf16x8*)((const char*)&Bs3[buf][(wc * 32 + ni * 8 + mh) * 64] + rdoff);
        asm volatile("s_waitcnt lgkmcnt(0)\ns_barrier" ::: "memory");
        __builtin_amdgcn_s_setprio(1);
#pragma unroll
        for (int mi = 0; mi < 8; ++mi)
#pragma unroll
            for (int ni = 0; ni < 4; ++ni)
                acc[mi][ni] = __builtin_amdgcn_mfma_f32_16x16x32_bf16(af[mi], bfr[ni], acc[mi][ni], 0, 0, 0);
        __builtin_amdgcn_s_setprio(0);
    };

    STAGE(0, 0);
    STAGE(1, 32);
    for (int t = 0; t < 30; ++t) {
        STAGE((t + 2) % 3, (t + 2) * 32);
        asm volatile("s_waitcnt vmcnt(8)\ns_barrier" ::: "memory");
        COMPUTE(t % 3);
    }
    asm volatile("s_waitcnt vmcnt(4)\ns_barrier" ::: "memory");
    COMPUTE(0);
    asm volatile("s_waitcnt vmcnt(0)\ns_barrier" ::: "memory");
    COMPUTE(1);

    int colw = colBase0 + wc * 64;
    int mtx = colw >> 10;
    int h = (colw >> 6) & 15;
    int rb = rowBase + wr * 128;

    if (mtx == 0) {
        const float qs = 0.125f * 1.44269504089f;   // fold 1/sqrt(E) and log2(e)
#pragma unroll
        for (int mi = 0; mi < 8; ++mi)
#pragma unroll
            for (int ni = 0; ni < 4; ++ni)
#pragma unroll
                for (int r = 0; r < 4; ++r) {
                    int row = rb + mi * 16 + g * 4 + r;
                    int b = row >> 11, s = row & 2047;
                    Qo[((size_t)(b * HH + h) * SS + s) * EE + ni * 16 + m] = f2bf(acc[mi][ni][r] * qs);
                }
    } else if (mtx == 1) {
#pragma unroll
        for (int mi = 0; mi < 8; ++mi)
#pragma unroll
            for (int ni = 0; ni < 4; ++ni)
#pragma unroll
                for (int r = 0; r < 4; ++r) {
                    int row = rb + mi * 16 + g * 4 + r;
                    int b = row >> 11, s = row & 2047;
                    Ko[((size_t)(b * HH + h) * SS + s) * EE + ni * 16 + m] = f2bf(acc[mi][ni][r]);
                }
    } else {
#pragma unroll
        for (int mi = 0; mi < 8; ++mi)
#pragma unroll
            for (int ni = 0; ni < 4; ++ni) {
                int row0 = rb + mi * 16 + g * 4;
                int b = row0 >> 11, s = row0 & 2047;
                s4 o; o[0] = f2bf(acc[mi][ni][0]); o[1] = f2bf(acc[mi][ni][1]);
                o[2] = f2bf(acc[mi][ni][2]); o[3] = f2bf(acc[mi][ni][3]);
                *(s4*)&Vto[((size_t)(b * HH + h) * EE + ni * 16 + m) * SS + s] = o;
            }
    }
}

// ------------- flash attention (causal): paired q-blocks, uniform 33 tiles/block -------------
// Block = 4 waves; processes q-block qblkA = 31-pair (tiles 0..qblkA) then
// qblkB = pair (tiles 0..qblkB): exactly 33 tiles for every block -> no tail.
// K/V double-buffered LDS (XOR-swizzled both sides), swapped QK^T lane-local
// softmax in exp2 domain, cvt_pk P-pack, defer-max 11.5 log2-units.
__global__ __launch_bounds__(256, 3) void attn_kernel(const short* __restrict__ Q,
                                                      const short* __restrict__ K,
                                                      const short* __restrict__ Vt,
                                                      short* __restrict__ ctx) {
    __shared__ __align__(16) short Ks[2][64 * 64];
    __shared__ __align__(16) short Vs[2][64 * 64];
    __shared__ __align__(16) short pl[4][16][72];
    int tid = threadIdx.x;
    int wv = tid >> 6, lane = tid & 63;
    int m = lane & 15, g = lane >> 4;
    int bid = blockIdx.x;
    int pair = bid >> 5;                 // 0..15
    int bh = bid & 31;
    int qblkA = 31 - pair, qblkB = pair; // 33 tiles total
    int b = bh >> 4, h = bh & 15;
    const short* Qb = Q + (size_t)bh * SS * EE;
    const short* Kb = K + (size_t)bh * SS * EE;
    const short* Vb = Vt + (size_t)bh * EE * SS;

    int srow = wv * 8 + (lane >> 3);
    int scol_s = (((lane & 7) * 16) ^ ((srow & 7) << 4)) >> 1;

    int sw = (m & 7) << 4;
    int c0 = (g * 16) ^ sw;
    int c1 = (64 + g * 16) ^ sw;

    auto STAGE = [&](int nb, int t0) {
        short* kd = &Ks[0][0] + nb * 4096 + wv * 512;
        short* vd = &Vs[0][0] + nb * 4096 + wv * 512;
        const short* ksrc = Kb + (size_t)(t0 + srow) * EE + scol_s;
        const short* vsrc = Vb + (size_t)srow * SS + t0 + scol_s;
        GLDS(ksrc, kd);
        GLDS(ksrc + 32 * EE, kd + 2048);
        GLDS(vsrc, vd);
        GLDS(vsrc + (size_t)32 * SS, vd + 2048);
    };

    // pass state (pass A first)
    int curQblk = qblkA;
    int qrow = qblkA * 64 + wv * 16 + m;
    bf16x8 qa0 = *(const bf16x8*)(Qb + (size_t)qrow * EE + g * 8);
    bf16x8 qa1 = *(const bf16x8*)(Qb + (size_t)qrow * EE + 32 + g * 8);
    float mreg = -INFINITY, lsum = 0.f;
    f32x4 o[4];
#pragma unroll
    for (int n = 0; n < 4; ++n) { o[n][0] = 0.f; o[n][1] = 0.f; o[n][2] = 0.f; o[n][3] = 0.f; }

    STAGE(0, 0);
    __syncthreads();

    int tt = 0;
    for (int s = 0; s < 33; ++s) {
        if (s + 1 < 33) {
            int nt = (s == qblkA) ? 0 : tt + 1;
            STAGE((s + 1) & 1, nt * 64);
        }
        int t0 = tt * 64;
        const short* Ksb = &Ks[0][0] + (s & 1) * 4096;
        const short* Vsb = &Vs[0][0] + (s & 1) * 4096;

        // S^T = K x Q (scores already in log2 domain via Q pre-scale)
        f32x4 sc[4] = {{0,0,0,0},{0,0,0,0},{0,0,0,0},{0,0,0,0}};
#pragma unroll
        for (int n = 0; n < 4; ++n) {
            const char* krow = (const char*)(Ksb + (n * 16 + m) * 64);
            bf16x8 kb0 = *(const bf16x8*)(krow + c0);
            sc[n] = __builtin_amdgcn_mfma_f32_16x16x32_bf16(kb0, qa0, sc[n], 0, 0, 0);
            bf16x8 kb1 = *(const bf16x8*)(krow + c1);
            sc[n] = __builtin_amdgcn_mfma_f32_16x16x32_bf16(kb1, qa1, sc[n], 0, 0, 0);
        }

        if (tt == curQblk) {          // diagonal tile of current pass
#pragma unroll
            for (int n = 0; n < 4; ++n)
#pragma unroll
                for (int r = 0; r < 4; ++r)
                    if (t0 + n * 16 + g * 4 + r > qrow) sc[n][r] = -INFINITY;
        }

        // row max: 15 in-lane fmax + 2 shuffles
        float mx = sc[0][0];
#pragma unroll
        for (int n = 0; n < 4; ++n)
#pragma unroll
            for (int r = 0; r < 4; ++r) mx = fmaxf(mx, sc[n][r]);
        mx = fmaxf(mx, __shfl_xor(mx, 16, 64));
        mx = fmaxf(mx, __shfl_xor(mx, 32, 64));

        // defer-max (11.5 log2-units ~ 8 nats)
        if (!__all(mx <= mreg + 11.5f)) {
            float mn = fmaxf(mreg, mx);
            float al = exp2f(mreg - mn);
            lsum *= al;
#pragma unroll
            for (int n = 0; n < 4; ++n)
#pragma unroll
                for (int r = 0; r < 4; ++r) o[n][r] *= al;
            mreg = mn;
        }

        // exp2 + partial sum + cvt_pk P pack to LDS
#pragma unroll
        for (int n = 0; n < 4; ++n) {
            float p0 = exp2f(sc[n][0] - mreg);
            float p1 = exp2f(sc[n][1] - mreg);
            float p2 = exp2f(sc[n][2] - mreg);
            float p3 = exp2f(sc[n][3] - mreg);
            lsum += (p0 + p1) + (p2 + p3);
            u32x2 pk; pk[0] = cvtpk(p0, p1); pk[1] = cvtpk(p2, p3);
            *(u32x2*)&pl[wv][m][n * 16 + g * 4] = pk;
        }

        // PV: o^T += V^T x P
#pragma unroll
        for (int ks = 0; ks < 2; ++ks) {
            bf16x8 pa = *(const bf16x8*)&pl[wv][m][ks * 32 + g * 8];
            int cv = ks ? c1 : c0;
#pragma unroll
            for (int n = 0; n < 4; ++n) {
                const char* vrow = (const char*)(Vsb + (n * 16 + m) * 64);
                bf16x8 vb = *(const bf16x8*)(vrow + cv);
                o[n] = __builtin_amdgcn_mfma_f32_16x16x32_bf16(vb, pa, o[n], 0, 0, 0);
            }
        }

        if (tt == curQblk) {
            // finalize current pass: reduce row-sum, write ctx
            float ls = lsum;
            ls += __shfl_xor(ls, 16, 64);
            ls += __shfl_xor(ls, 32, 64);
            float inv = 1.0f / ls;
            short* cb = ctx + (size_t)(b * SS + qrow) * (HH * EE) + h * EE;
#pragma unroll
            for (int n = 0; n < 4; ++n) {
                u32x2 k0; k0[0] = cvtpk(o[n][0] * inv, o[n][1] * inv);
                k0[1] = cvtpk(o[n][2] * inv, o[n][3] * inv);
                *(u32x2*)&cb[n * 16 + g * 4] = k0;
            }
            if (s != 32) {
                // switch to pass B
                curQblk = qblkB;
                qrow = qblkB * 64 + wv * 16 + m;
                qa0 = *(const bf16x8*)(Qb + (size_t)qrow * EE + g * 8);
                qa1 = *(const bf16x8*)(Qb + (size_t)qrow * EE + 32 + g * 8);
                mreg = -INFINITY; lsum = 0.f;
#pragma unroll
                for (int n = 0; n < 4; ++n) { o[n][0] = 0.f; o[n][1] = 0.f; o[n][2] = 0.f; o[n][3] = 0.f; }
                tt = -1;
            }
        }
        ++tt;
        __syncthreads();
    }
}

// ------------- output projection: ctx [4096,1024] @ W [1024,64] -> out fp32 -------------
__global__ __launch_bounds__(256) void outproj_kernel(const short* __restrict__ ctx,
                                                      const short* __restrict__ wot,
                                                      float* __restrict__ out) {
    __shared__ float red[4][1024];
    int wv = threadIdx.x >> 6, lane = threadIdx.x & 63;
    int m = lane & 15, g = lane >> 4;
    int r0 = blockIdx.x * 16;
    const short* arow = ctx + (size_t)(r0 + m) * (HH * EE) + g * 8;
    const short* wb = wot + g * 8;
    f32x4 acc[4] = {{0,0,0,0},{0,0,0,0},{0,0,0,0},{0,0,0,0}};
    int k0 = wv * 256;
    for (int d0 = k0; d0 < k0 + 256; d0 += 32) {
        bf16x8 a = *(const bf16x8*)(arow + d0);
#pragma unroll
        for (int n = 0; n < 4; ++n) {
            bf16x8 bbf = *(const bf16x8*)(wb + (size_t)(n * 16 + m) * (HH * EE) + d0);
            acc[n] = __builtin_amdgcn_mfma_f32_16x16x32_bf16(a, bbf, acc[n], 0, 0, 0);
        }
    }
#pragma unroll
    for (int n = 0; n < 4; ++n)
#pragma unroll
        for (int r = 0; r < 4; ++r)
            red[wv][(g * 4 + r) * 64 + n * 16 + m] = acc[n][r];
    __syncthreads();
    int t = threadIdx.x;
    float4v sum = ((const float4v*)red[0])[t];
    sum += ((const float4v*)red[1])[t];
    sum += ((const float4v*)red[2])[t];
    sum += ((const float4v*)red[3])[t];
    ((float4v*)(out + (size_t)blockIdx.x * 1024))[t] = sum;
}

extern "C" void kernel_launch(void* const* d_in, const int* in_sizes, int n_in,
                              void* d_out, int out_size, void* d_ws, size_t ws_size,
                              hipStream_t stream) {
    const float* x  = (const float*)d_in[0];
    const float* Wq = (const float*)d_in[1];
    const float* Wk = (const float*)d_in[2];
    const float* Wv = (const float*)d_in[3];
    const float* W  = (const float*)d_in[4];
    float* out = (float*)d_out;

    char* w = (char*)d_ws;
    short* xb  = (short*)w;                                   // 8 MB
    short* wqt = (short*)(w + ((size_t)8 << 20));             // 2 MB each, contiguous = Bt
    short* wot = wqt + (size_t)3 * HH * EE * DD;              // 128 KB
    short* Qb  = wot + (size_t)64 * 1024;                     // 8 MB each
    short* Kb  = Qb + (size_t)BB * HH * SS * EE;
    short* Vtb = Kb + (size_t)BB * HH * SS * EE;
    short* ctx = Vtb + (size_t)BB * HH * SS * EE;             // 8 MB

    prep_kernel<<<4880, 256, 0, stream>>>(x, Wq, Wk, Wv, W, xb, wqt, wot);
    qkv_gemm<<<192, 512, 0, stream>>>(xb, wqt, Qb, Kb, Vtb);
    attn_kernel<<<512, 256, 0, stream>>>(Qb, Kb, Vtb, ctx);
    outproj_kernel<<<256, 256, 0, stream>>>(ctx, wot, out);
}